// Round 15
// baseline (136.332 us; speedup 1.0000x reference)
//
#include <hip/hip_runtime.h>

// hd_id_lvl_decoder: scores[b,i,l] = sum_d x[b,d]*id[i,d]*lvl[l,d]; out[b,i] = argmax_l * 0.015625
// B=64, NUM_ID=256, NUM_LVL=64, D=10000.
//
// f16x2-split MFMA, 3-term (hh + hl + lh; ll dropped ~6e-6, below fp32 noise).
// R15 = R7's proven structure (schedule/LDS/staging byte-identical; R8-R14: seven deviations,
// seven regressions) with the MFMA shape switched 16x16x32 -> 32x32x16: same LDS traffic
// (tile geometry unchanged), half the MFMA instructions at the higher 32x32 rate
// (24x~8cyc = 192 vs 48x~4.85 = 233 cyc/chunk/wave), freed issue slots at 2 waves/SIMD.
// A/B frag: m=lane&31, k=(lane>>5)*8+e. C/D: col=lane&31, row=(reg&3)+8*(reg>>2)+4*(lane>>5).
// Phase 2: one wave per (b,i), lane = l: fp64 sum of S partials, shfl_xor argmax (first ties).

typedef _Float16 f16x8 __attribute__((ext_vector_type(8)));
typedef float f32x16 __attribute__((ext_vector_type(16)));

constexpr int D    = 10000;
constexpr int KPAD = 10016;            // 313 * 32
constexpr int B    = 64;
constexpr int NI   = 256;
constexpr int NL   = 64;
constexpr int BK   = 32;
constexpr int NCH  = KPAD / BK;        // 313 chunks
constexpr int S    = 8;                // k-splits
constexpr int BM   = 128;              // i per block
constexpr float BIN_LEN = 0.015625f;

// ws layout (bytes): [0, 32M) partials; then idh (256*10016 f16), idl.
constexpr size_t OFF_IDH = (size_t)S * B * NI * NL * 4;          // 33,554,432
constexpr size_t IDSZ    = (size_t)NI * KPAD;                     // elements per id array

__device__ __forceinline__ float4 ld4(const float* p) {
    return *reinterpret_cast<const float4*>(p);
}

// ---------------- Phase 0: split id into f16 hi/lo, zero-pad to KPAD ----------------
__global__ __launch_bounds__(256)
void hd_split_id(const float* __restrict__ id_hvs,
                 _Float16* __restrict__ idh, _Float16* __restrict__ idl) {
    const int i = blockIdx.x;          // 256 blocks, one i-row each
    for (int k = threadIdx.x; k < KPAD; k += 256) {
        float v = (k < D) ? id_hvs[(size_t)i * D + k] : 0.0f;
        _Float16 h = (_Float16)v;
        _Float16 lo = (_Float16)(v - (float)h);
        idh[(size_t)i * KPAD + k] = h;
        idl[(size_t)i * KPAD + k] = lo;
    }
}

// ---------------- Phase 1: MFMA main kernel ----------------
__global__ __launch_bounds__(256)
void hd_mfma(const float* __restrict__ x, const float* __restrict__ lvl_hvs,
             const _Float16* __restrict__ idh, const _Float16* __restrict__ idl,
             float* __restrict__ part) {
    // slot = kg ^ ((row>>1)&3) swizzle -> conflict-free (R6/R7 measured: 0)
    __shared__ f16x8 sA[2][2][BM][4];       // id tiles   [buf][hi/lo][row][slot], 32 KB
    __shared__ f16x8 sW[2][2][2][NL][4];    // w tiles    [buf][hi/lo][b][row][slot], 32 KB

    const int tid = threadIdx.x;
    const int bx  = blockIdx.x;
    const int s     = bx >> 6;          // 0..S-1
    const int ibase = (bx & 1) * BM;    // 0 or 128
    const int b0    = ((bx >> 1) & 31) * 2;

    // chunk range for this split
    const int cb = NCH / S, cr = NCH % S;          // 39, 1
    const int cstart = s * cb + (s < cr ? s : cr);
    const int nch    = cb + (s < cr ? 1 : 0);

    // w staging: thread -> lvl row (tid>>2)&63, kg tid&3
    const int w_row = (tid >> 2) & 63, w_kg = tid & 3;
    const int w_slot = w_kg ^ ((w_row >> 1) & 3);

    // wave / fragment decode: 4 waves as 2(i) x 2(b); 32x32 fragments
    const int wid = tid >> 6;
    const int wm = wid >> 1, wn = wid & 1;          // rows [wm*64,+64), b = b0+wn
    const int m31 = tid & 31, half = (tid >> 5) & 1;

    f32x16 accM[2][2], accC[2][2];
#pragma unroll
    for (int rt = 0; rt < 2; ++rt)
#pragma unroll
        for (int ct = 0; ct < 2; ++ct) {
            accM[rt][ct] = (f32x16)0.0f;
            accC[rt][ct] = (f32x16)0.0f;
        }

    f16x8 r_id[4];
    float r_lv[8], r_x0[8], r_x1[8];

    auto LOAD_A = [&](int c) {
        const int k0 = (cstart + c) * BK;
#pragma unroll
        for (int m = 0; m < 4; ++m) {
            int u = tid + 256 * m;
            int arr = u >> 9, u2 = u & 511;
            int row = u2 >> 2, kg = u2 & 3;
            const _Float16* src = (arr ? idl : idh)
                + (size_t)(ibase + row) * KPAD + k0 + kg * 8;
            r_id[m] = *reinterpret_cast<const f16x8*>(src);
        }
    };

    auto WRITE_A = [&](int buf) {
#pragma unroll
        for (int m = 0; m < 4; ++m) {
            int u = tid + 256 * m;
            int arr = u >> 9, u2 = u & 511;
            int row = u2 >> 2, kg = u2 & 3;
            sA[buf][arr][row][kg ^ ((row >> 1) & 3)] = r_id[m];
        }
    };

    auto LOAD_W = [&](int c) {
        const int k0 = (cstart + c) * BK;
        const int kb = k0 + w_kg * 8;
        const float* lp  = lvl_hvs + (size_t)w_row * D + kb;
        const float* xp0 = x + (size_t)b0 * D + kb;
        const float* xp1 = xp0 + D;
        if (kb + 8 <= D) {
            float4 a0 = ld4(lp),  a1 = ld4(lp + 4);
            float4 c0 = ld4(xp0), c1 = ld4(xp0 + 4);
            float4 d0 = ld4(xp1), d1 = ld4(xp1 + 4);
            r_lv[0] = a0.x; r_lv[1] = a0.y; r_lv[2] = a0.z; r_lv[3] = a0.w;
            r_lv[4] = a1.x; r_lv[5] = a1.y; r_lv[6] = a1.z; r_lv[7] = a1.w;
            r_x0[0] = c0.x; r_x0[1] = c0.y; r_x0[2] = c0.z; r_x0[3] = c0.w;
            r_x0[4] = c1.x; r_x0[5] = c1.y; r_x0[6] = c1.z; r_x0[7] = c1.w;
            r_x1[0] = d0.x; r_x1[1] = d0.y; r_x1[2] = d0.z; r_x1[3] = d0.w;
            r_x1[4] = d1.x; r_x1[5] = d1.y; r_x1[6] = d1.z; r_x1[7] = d1.w;
        } else {
#pragma unroll
            for (int e = 0; e < 8; ++e) {
                bool in = (kb + e) < D;
                r_lv[e] = in ? lp[e]  : 0.0f;
                r_x0[e] = in ? xp0[e] : 0.0f;
                r_x1[e] = in ? xp1[e] : 0.0f;
            }
        }
    };

    auto WRITE_W = [&](int buf) {
#pragma unroll
        for (int bs = 0; bs < 2; ++bs) {
            const float* rx = bs ? r_x1 : r_x0;
            f16x8 h, lo;
#pragma unroll
            for (int e = 0; e < 8; ++e) {
                float w = rx[e] * r_lv[e];
                _Float16 hh = (_Float16)w;
                h[e] = hh;
                lo[e] = (_Float16)(w - (float)hh);
            }
            sW[buf][0][bs][w_row][w_slot] = h;
            sW[buf][1][bs][w_row][w_slot] = lo;
        }
    };

    auto COMPUTE = [&](int buf) {
#pragma unroll
        for (int ks = 0; ks < 2; ++ks) {            // two K=16 steps per BK=32 chunk
            const int kg = ks * 2 + half;           // lane's k-group: k = kg*8 + e
            f16x8 bh[2], bl[2], ah[2], al[2];
#pragma unroll
            for (int ct = 0; ct < 2; ++ct) {
                int col = ct * 32 + m31;
                int slot = kg ^ ((col >> 1) & 3);
                bh[ct] = sW[buf][0][wn][col][slot];
                bl[ct] = sW[buf][1][wn][col][slot];
            }
#pragma unroll
            for (int rt = 0; rt < 2; ++rt) {
                int row = wm * 64 + rt * 32 + m31;
                int slot = kg ^ ((row >> 1) & 3);
                ah[rt] = sA[buf][0][row][slot];
                al[rt] = sA[buf][1][row][slot];
            }
#pragma unroll
            for (int rt = 0; rt < 2; ++rt)
#pragma unroll
                for (int ct = 0; ct < 2; ++ct) {
                    accM[rt][ct] = __builtin_amdgcn_mfma_f32_32x32x16_f16(ah[rt], bh[ct], accM[rt][ct], 0, 0, 0);
                    accC[rt][ct] = __builtin_amdgcn_mfma_f32_32x32x16_f16(ah[rt], bl[ct], accC[rt][ct], 0, 0, 0);
                    accC[rt][ct] = __builtin_amdgcn_mfma_f32_32x32x16_f16(al[rt], bh[ct], accC[rt][ct], 0, 0, 0);
                }
        }
    };

    // prologue: chunk 0 staged
    LOAD_A(0);
    LOAD_W(0);
    WRITE_A(0);
    WRITE_W(0);
    __syncthreads();

    int cur = 0;
    for (int c = 0; c < nch; ++c) {
        const bool more = (c + 1 < nch);
        if (more) { LOAD_A(c + 1); LOAD_W(c + 1); }   // issue global loads early (T14)
        COMPUTE(cur);
        if (more) { WRITE_A(cur ^ 1); WRITE_W(cur ^ 1); }
        __syncthreads();
        cur ^= 1;
    }

    // epilogue: 32x32 C/D layout col=lane&31, row=(reg&3)+8*(reg>>2)+4*half.
    float* outp = part + (size_t)(s * B + b0 + wn) * NI * NL;
#pragma unroll
    for (int rt = 0; rt < 2; ++rt) {
#pragma unroll
        for (int ct = 0; ct < 2; ++ct) {
            const int l = ct * 32 + m31;
#pragma unroll
            for (int r = 0; r < 16; ++r) {
                const int row_off = (r & 3) + 8 * (r >> 2) + 4 * half;
                const int i0 = ibase + wm * 64 + rt * 32 + row_off;
                outp[(size_t)i0 * NL + l] = accM[rt][ct][r] + accC[rt][ct][r];
            }
        }
    }
}

// ---------------- Phase 2: fp64 combine + argmax (one wave per (b,i)) ----------------
__global__ __launch_bounds__(256)
void hd_phase2(const float* __restrict__ ws, float* __restrict__ out, int SS) {
    const int wid  = blockIdx.x * 4 + (threadIdx.x >> 6);   // (b,i) flat index
    const int lane = threadIdx.x & 63;                       // l
    const int b = wid >> 8, i = wid & 255;
    const float* p = ws + ((size_t)b * NI + i) * NL + lane;
    const size_t sstride = (size_t)B * NI * NL;              // 1,048,576

    double s0 = 0.0, s1 = 0.0, s2 = 0.0, s3 = 0.0;
    int ss = 0;
    for (; ss + 4 <= SS; ss += 4) {
        s0 += (double)p[(size_t)(ss + 0) * sstride];
        s1 += (double)p[(size_t)(ss + 1) * sstride];
        s2 += (double)p[(size_t)(ss + 2) * sstride];
        s3 += (double)p[(size_t)(ss + 3) * sstride];
    }
    for (; ss < SS; ++ss) s0 += (double)p[(size_t)ss * sstride];

    double mv = (s0 + s1) + (s2 + s3);
    int mi = lane;
#pragma unroll
    for (int off = 1; off < 64; off <<= 1) {
        double ov = __shfl_xor(mv, off);
        int   oi  = __shfl_xor(mi, off);
        if (ov > mv || (ov == mv && oi < mi)) { mv = ov; mi = oi; }  // first-index tie-break
    }
    if (lane == 0) out[wid] = (float)mi * BIN_LEN;
}

extern "C" void kernel_launch(void* const* d_in, const int* in_sizes, int n_in,
                              void* d_out, int out_size, void* d_ws, size_t ws_size,
                              hipStream_t stream) {
    const float* x       = (const float*)d_in[0];
    const float* id_hvs  = (const float*)d_in[1];
    const float* lvl_hvs = (const float*)d_in[2];
    float* out = (float*)d_out;

    float*     part = (float*)d_ws;
    _Float16*  idh  = (_Float16*)((char*)d_ws + OFF_IDH);
    _Float16*  idl  = idh + IDSZ;

    hd_split_id<<<dim3(NI), dim3(256), 0, stream>>>(id_hvs, idh, idl);
    // 512 blocks: S x 32 b-pairs x 2 i-tiles
    hd_mfma<<<dim3(S * 64), dim3(256), 0, stream>>>(x, lvl_hvs, idh, idl, part);
    hd_phase2<<<dim3(B * NI / 4), dim3(256), 0, stream>>>(part, out, S);
}